// Round 1
// baseline (470.083 us; speedup 1.0000x reference)
//
#include <hip/hip_runtime.h>
#include <math.h>

// B=64, T=2048, H=512, Q=512
// energies[b,t] = enc[b,t,:] . v[b,:] + c[b]
//   v[b,h] = sum_q query[b,q] * W[q,h]   (W row-major [Q,H])
//   c[b]   = query[b,:] . bias
// softmax over t < len=tgt[b]+1; context[b,:] = sum_t p[b,t] * enc[b,t,:]
//
// 2-kernel version:
//   k_proj: vectorized (float4 W loads, 4 waves = 4 q-quarters, LDS reduce);
//           also zeroes the per-batch completion counters (poison-safe init).
//   k_attn: single-pass flash (enc read once) + FUSED combine — the last
//           chunk-block per batch (device-scope atomic counter) reduces the
//           chunk partials and writes out[b]. No spin-waits -> no deadlock.

#define B 64
#define T 2048
#define H 512
#define Q 512
#define TT 128          // rows per block-chunk
#define NCH (T / TT)    // 16 chunks per batch

// ---------------------------------------------------------------- kernel 1
// grid (2, B), block 256 (4 waves). Wave qq owns q in [qq*128, qq*128+128);
// lane owns h4 = blockIdx.x*256 + lane*4 (float4 of W row -> 1KB/wave/instr).
__global__ __launch_bounds__(256) void k_proj(const float* __restrict__ query,
                                              const float* __restrict__ W,
                                              const float* __restrict__ bias,
                                              float* __restrict__ v,
                                              float* __restrict__ c,
                                              int* __restrict__ cnt) {
    int b = blockIdx.y;
    int tid = threadIdx.x;
    int lane = tid & 63;
    int qq = tid >> 6;                      // wave index = q-quarter
    int h4 = blockIdx.x * 256 + lane * 4;

    __shared__ float sq[Q];
    ((float2*)sq)[tid] = ((const float2*)(query + (size_t)b * Q))[tid];
    __syncthreads();

    float4 acc = {0.f, 0.f, 0.f, 0.f};
    const float* Wp = W + (size_t)(qq * 128) * H + h4;
#pragma unroll 8
    for (int q = 0; q < 128; ++q) {
        float s = sq[qq * 128 + q];
        const float4 w = *(const float4*)(Wp + (size_t)q * H);
        acc.x += s * w.x; acc.y += s * w.y;
        acc.z += s * w.z; acc.w += s * w.w;
    }

    __shared__ float4 sp[4][64];
    sp[qq][lane] = acc;
    __syncthreads();
    if (qq == 0) {
        float4 r0 = sp[0][lane], r1 = sp[1][lane];
        float4 r2 = sp[2][lane], r3 = sp[3][lane];
        float4 r;
        r.x = (r0.x + r1.x) + (r2.x + r3.x);
        r.y = (r0.y + r1.y) + (r2.y + r3.y);
        r.z = (r0.z + r1.z) + (r2.z + r3.z);
        r.w = (r0.w + r1.w) + (r2.w + r3.w);
        ((float4*)(v + (size_t)b * H))[blockIdx.x * 64 + lane] = r;
    }

    if (blockIdx.x == 0) {
        // c[b] = query[b,:] . bias  (256 threads x 2 terms, wave+LDS reduce)
        float pb = sq[tid] * bias[tid] + sq[tid + 256] * bias[tid + 256];
        for (int off = 32; off; off >>= 1) pb += __shfl_xor(pb, off, 64);
        __shared__ float sred[4];
        if (lane == 0) sred[qq] = pb;
        __syncthreads();
        if (tid == 0) {
            c[b] = (sred[0] + sred[1]) + (sred[2] + sred[3]);
            cnt[b] = 0;                 // completion counter (poison-safe)
        }
    }
}

// ---------------------------------------------------------------- kernel 2
// grid (NCH, B), block 256 (4 waves). Wave w owns quads starting at
// t = 4w + 16j within its 128-row chunk. Last finishing chunk-block of a
// batch (atomic counter) performs the cross-chunk combine and writes out.
__global__ __launch_bounds__(256) void k_attn(const float* __restrict__ enc,
                                              const float* __restrict__ v,
                                              const float* __restrict__ c,
                                              const int* __restrict__ tgt,
                                              float* __restrict__ pm,
                                              float* __restrict__ pl,
                                              float* __restrict__ pctx,
                                              int* __restrict__ cnt,
                                              float* __restrict__ out) {
    int b = blockIdx.y;
    int len = tgt[b] + 1;
    int t0 = blockIdx.x * TT;
    if (t0 >= len) return;               // inactive chunk: no atomic bump
    int n = min(TT, len - t0);
    int nch = (len + TT - 1) / TT;       // number of active chunks for b

    int tid = threadIdx.x;
    int wave = tid >> 6;
    int lane = tid & 63;

    const float4* v4 = (const float4*)(v + (size_t)b * H);
    float4 w0 = v4[lane];
    float4 w1 = v4[lane + 64];
    float cb = c[b];

    float m = -INFINITY, l = 0.0f;
    float4 a0 = {0.f,0.f,0.f,0.f}, a1 = {0.f,0.f,0.f,0.f};
    const float* encb = enc + ((size_t)b * T + t0) * H;

    for (int t = wave * 4; t < n; t += 16) {
        const float4* r0 = (const float4*)(encb + (size_t)(t + 0) * H);
        const float4* r1 = (const float4*)(encb + (size_t)(t + 1) * H);
        const float4* r2 = (const float4*)(encb + (size_t)(t + 2) * H);
        const float4* r3 = (const float4*)(encb + (size_t)(t + 3) * H);
        float4 x00 = r0[lane], x01 = r0[lane + 64];
        float4 x10 = r1[lane], x11 = r1[lane + 64];
        float4 x20 = r2[lane], x21 = r2[lane + 64];
        float4 x30 = r3[lane], x31 = r3[lane + 64];

        float e0 = x00.x*w0.x + x00.y*w0.y + x00.z*w0.z + x00.w*w0.w
                 + x01.x*w1.x + x01.y*w1.y + x01.z*w1.z + x01.w*w1.w;
        float e1 = x10.x*w0.x + x10.y*w0.y + x10.z*w0.z + x10.w*w0.w
                 + x11.x*w1.x + x11.y*w1.y + x11.z*w1.z + x11.w*w1.w;
        float e2 = x20.x*w0.x + x20.y*w0.y + x20.z*w0.z + x20.w*w0.w
                 + x21.x*w1.x + x21.y*w1.y + x21.z*w1.z + x21.w*w1.w;
        float e3 = x30.x*w0.x + x30.y*w0.y + x30.z*w0.z + x30.w*w0.w
                 + x31.x*w1.x + x31.y*w1.y + x31.z*w1.z + x31.w*w1.w;

        // 4 interleaved butterfly reduces — latency amortized 4x
        for (int off = 32; off; off >>= 1) {
            e0 += __shfl_xor(e0, off, 64);
            e1 += __shfl_xor(e1, off, 64);
            e2 += __shfl_xor(e2, off, 64);
            e3 += __shfl_xor(e3, off, 64);
        }
        e0 += cb;                            // t+0 < n by loop condition
        e1 = (t + 1 < n) ? e1 + cb : -INFINITY;
        e2 = (t + 2 < n) ? e2 + cb : -INFINITY;
        e3 = (t + 3 < n) ? e3 + cb : -INFINITY;

        float mn = fmaxf(fmaxf(fmaxf(e0, e1), fmaxf(e2, e3)), m);
        float alpha = __expf(m - mn);        // first iter: exp(-inf)=0
        float p0 = __expf(e0 - mn);
        float p1 = __expf(e1 - mn);          // masked rows -> 0
        float p2 = __expf(e2 - mn);
        float p3 = __expf(e3 - mn);
        l = l * alpha + (p0 + p1) + (p2 + p3);
        a0.x = a0.x*alpha + p0*x00.x + p1*x10.x + p2*x20.x + p3*x30.x;
        a0.y = a0.y*alpha + p0*x00.y + p1*x10.y + p2*x20.y + p3*x30.y;
        a0.z = a0.z*alpha + p0*x00.z + p1*x10.z + p2*x20.z + p3*x30.z;
        a0.w = a0.w*alpha + p0*x00.w + p1*x10.w + p2*x20.w + p3*x30.w;
        a1.x = a1.x*alpha + p0*x01.x + p1*x11.x + p2*x21.x + p3*x31.x;
        a1.y = a1.y*alpha + p0*x01.y + p1*x11.y + p2*x21.y + p3*x31.y;
        a1.z = a1.z*alpha + p0*x01.z + p1*x11.z + p2*x21.z + p3*x31.z;
        a1.w = a1.w*alpha + p0*x01.w + p1*x11.w + p2*x21.w + p3*x31.w;
        m = mn;
    }

    // ---- block-level merge of the 4 wave partials via LDS ----
    __shared__ float sm4[4], sl4[4];
    __shared__ float sctx[4 * H];            // 8 KB
    float4* sc = (float4*)(sctx + wave * H);
    sc[lane]      = a0;
    sc[lane + 64] = a1;
    if (lane == 0) { sm4[wave] = m; sl4[wave] = l; }
    __syncthreads();

    float M = fmaxf(fmaxf(sm4[0], sm4[1]), fmaxf(sm4[2], sm4[3]));  // finite
    float L = 0.0f, acc0 = 0.0f, acc1 = 0.0f;
#pragma unroll
    for (int j = 0; j < 4; ++j) {
        float mj = sm4[j];
        float wj = (mj == -INFINITY) ? 0.0f : __expf(mj - M);
        L += sl4[j] * wj;
        acc0 += wj * sctx[j * H + 2 * tid];
        acc1 += wj * sctx[j * H + 2 * tid + 1];
    }
    int pidx = b * NCH + blockIdx.x;
    if (tid == 0) { pm[pidx] = M; pl[pidx] = L; }
    float2* dst = (float2*)(pctx + (size_t)pidx * H);
    dst[tid] = make_float2(acc0, acc1);

    // ---- last-block-per-batch combine ----
    // __syncthreads drains every thread's stores (vmcnt(0) before s_barrier),
    // so one release fence + device-scope atomic from tid 0 publishes the
    // whole block's partials.
    __syncthreads();
    __shared__ int slast;
    if (tid == 0) {
        __threadfence();                              // release
        slast = (atomicAdd(&cnt[b], 1) == nch - 1);
    }
    __syncthreads();
    if (!slast) return;
    __threadfence();                                  // acquire (all threads)

    __shared__ float spm[NCH], spl[NCH];
    if (tid < nch) {
        spm[tid] = pm[b * NCH + tid];
        spl[tid] = pl[b * NCH + tid];
    }
    __syncthreads();

    float M2 = -INFINITY;
    for (int j = 0; j < nch; ++j) M2 = fmaxf(M2, spm[j]);
    float L2 = 0.0f;
    for (int j = 0; j < nch; ++j) L2 += spl[j] * __expf(spm[j] - M2);
    float invL = 1.0f / L2;

    float o0 = 0.0f, o1 = 0.0f;
    for (int j = 0; j < nch; ++j) {
        float wj = __expf(spm[j] - M2) * invL;
        float2 x = ((const float2*)(pctx + (size_t)(b * NCH + j) * H))[tid];
        o0 += wj * x.x;
        o1 += wj * x.y;
    }
    out[(size_t)b * H + 2 * tid]     = o0;
    out[(size_t)b * H + 2 * tid + 1] = o1;
}

// ---------------------------------------------------------------- launch
extern "C" void kernel_launch(void* const* d_in, const int* in_sizes, int n_in,
                              void* d_out, int out_size, void* d_ws, size_t ws_size,
                              hipStream_t stream) {
    const float* query = (const float*)d_in[0];   // [B,Q]
    const float* enc   = (const float*)d_in[1];   // [B,T,H]
    const float* W     = (const float*)d_in[2];   // [Q,H]
    const float* bias  = (const float*)d_in[3];   // [Q]
    const int*   tgt   = (const int*)d_in[4];     // [B]
    float* out = (float*)d_out;                   // [B,H]

    char* ws = (char*)d_ws;
    float* v    = (float*)ws;  ws += (size_t)B * H * sizeof(float);
    float* c    = (float*)ws;  ws += 256;
    float* pm   = (float*)ws;  ws += (size_t)B * NCH * sizeof(float);
    float* pl   = (float*)ws;  ws += (size_t)B * NCH * sizeof(float);
    float* pctx = (float*)ws;  ws += (size_t)B * NCH * H * sizeof(float); // 2 MB
    int*   cnt  = (int*)ws;    // B ints, zeroed by k_proj each iteration

    k_proj<<<dim3(2, B), dim3(256), 0, stream>>>(query, W, bias, v, c, cnt);
    k_attn<<<dim3(NCH, B), dim3(256), 0, stream>>>(enc, v, c, tgt,
                                                   pm, pl, pctx, cnt, out);
}

// Round 2
// 354.413 us; speedup vs baseline: 1.3264x; 1.3264x over previous
//
#include <hip/hip_runtime.h>
#include <math.h>

// B=64, T=2048, H=512, Q=512
// energies[b,t] = enc[b,t,:] . v[b,:] + c[b]
//   v[b,h] = sum_q query[b,q] * W[q,h]   (W row-major [Q,H])
//   c[b]   = query[b,:] . bias
// softmax over t < len=tgt[b]+1; context[b,:] = sum_t p[b,t] * enc[b,t,:]
//
// 3-kernel version (fusion via device-scope fences REGRESSED — reverted).
// k_attn occupancy fix: TT=32 (64 chunks/batch, 4096 blocks) so the active
// wave count ~fills the machine; each wave does 2 quad-iterations and TLP
// hides the HBM latency that previously serialized (round-1 counters:
// occupancy 8.6%, VALUBusy 1.8%, HBM 4.4% -> pure latency-bound).

#define B 64
#define T 2048
#define H 512
#define Q 512
#define TT 32           // rows per block-chunk
#define NCH (T / TT)    // 64 chunks per batch

// ---------------------------------------------------------------- kernel 1
// grid (2, B), block 256 (4 waves). Wave qq owns q in [qq*128, qq*128+128);
// lane owns h4 = blockIdx.x*256 + lane*4 (float4 W loads, 1KB/wave/instr).
__global__ __launch_bounds__(256) void k_proj(const float* __restrict__ query,
                                              const float* __restrict__ W,
                                              const float* __restrict__ bias,
                                              float* __restrict__ v,
                                              float* __restrict__ c) {
    int b = blockIdx.y;
    int tid = threadIdx.x;
    int lane = tid & 63;
    int qq = tid >> 6;                      // wave index = q-quarter
    int h4 = blockIdx.x * 256 + lane * 4;

    __shared__ float sq[Q];
    ((float2*)sq)[tid] = ((const float2*)(query + (size_t)b * Q))[tid];
    __syncthreads();

    float4 acc = {0.f, 0.f, 0.f, 0.f};
    const float* Wp = W + (size_t)(qq * 128) * H + h4;
#pragma unroll 8
    for (int q = 0; q < 128; ++q) {
        float s = sq[qq * 128 + q];
        const float4 w = *(const float4*)(Wp + (size_t)q * H);
        acc.x += s * w.x; acc.y += s * w.y;
        acc.z += s * w.z; acc.w += s * w.w;
    }

    __shared__ float4 sp[4][64];
    sp[qq][lane] = acc;
    __syncthreads();
    if (qq == 0) {
        float4 r0 = sp[0][lane], r1 = sp[1][lane];
        float4 r2 = sp[2][lane], r3 = sp[3][lane];
        float4 r;
        r.x = (r0.x + r1.x) + (r2.x + r3.x);
        r.y = (r0.y + r1.y) + (r2.y + r3.y);
        r.z = (r0.z + r1.z) + (r2.z + r3.z);
        r.w = (r0.w + r1.w) + (r2.w + r3.w);
        ((float4*)(v + (size_t)b * H))[blockIdx.x * 64 + lane] = r;
    }

    if (blockIdx.x == 0) {
        // c[b] = query[b,:] . bias  (256 threads x 2 terms, wave+LDS reduce)
        float pb = sq[tid] * bias[tid] + sq[tid + 256] * bias[tid + 256];
        for (int off = 32; off; off >>= 1) pb += __shfl_xor(pb, off, 64);
        __shared__ float sred[4];
        if (lane == 0) sred[qq] = pb;
        __syncthreads();
        if (tid == 0) c[b] = (sred[0] + sred[1]) + (sred[2] + sred[3]);
    }
}

// ---------------------------------------------------------------- kernel 2
// grid (NCH, B) = (64, 64), block 256 (4 waves). Wave w owns quads starting
// at t = 4w + 16j within its 32-row chunk (2 iterations per wave).
__global__ __launch_bounds__(256) void k_attn(const float* __restrict__ enc,
                                              const float* __restrict__ v,
                                              const float* __restrict__ c,
                                              const int* __restrict__ tgt,
                                              float* __restrict__ pm,
                                              float* __restrict__ pl,
                                              float* __restrict__ pctx) {
    int b = blockIdx.y;
    int len = tgt[b] + 1;
    int t0 = blockIdx.x * TT;
    if (t0 >= len) return;               // uniform early exit, no sync before
    int n = min(TT, len - t0);

    int tid = threadIdx.x;
    int wave = tid >> 6;
    int lane = tid & 63;

    const float4* v4 = (const float4*)(v + (size_t)b * H);
    float4 w0 = v4[lane];
    float4 w1 = v4[lane + 64];
    float cb = c[b];

    float m = -INFINITY, l = 0.0f;
    float4 a0 = {0.f,0.f,0.f,0.f}, a1 = {0.f,0.f,0.f,0.f};
    const float* encb = enc + ((size_t)b * T + t0) * H;

    for (int t = wave * 4; t < n; t += 16) {
        const float4* r0 = (const float4*)(encb + (size_t)(t + 0) * H);
        const float4* r1 = (const float4*)(encb + (size_t)(t + 1) * H);
        const float4* r2 = (const float4*)(encb + (size_t)(t + 2) * H);
        const float4* r3 = (const float4*)(encb + (size_t)(t + 3) * H);
        float4 x00 = r0[lane], x01 = r0[lane + 64];
        float4 x10 = r1[lane], x11 = r1[lane + 64];
        float4 x20 = r2[lane], x21 = r2[lane + 64];
        float4 x30 = r3[lane], x31 = r3[lane + 64];

        float e0 = x00.x*w0.x + x00.y*w0.y + x00.z*w0.z + x00.w*w0.w
                 + x01.x*w1.x + x01.y*w1.y + x01.z*w1.z + x01.w*w1.w;
        float e1 = x10.x*w0.x + x10.y*w0.y + x10.z*w0.z + x10.w*w0.w
                 + x11.x*w1.x + x11.y*w1.y + x11.z*w1.z + x11.w*w1.w;
        float e2 = x20.x*w0.x + x20.y*w0.y + x20.z*w0.z + x20.w*w0.w
                 + x21.x*w1.x + x21.y*w1.y + x21.z*w1.z + x21.w*w1.w;
        float e3 = x30.x*w0.x + x30.y*w0.y + x30.z*w0.z + x30.w*w0.w
                 + x31.x*w1.x + x31.y*w1.y + x31.z*w1.z + x31.w*w1.w;

        // 4 interleaved butterfly reduces — latency amortized 4x
        for (int off = 32; off; off >>= 1) {
            e0 += __shfl_xor(e0, off, 64);
            e1 += __shfl_xor(e1, off, 64);
            e2 += __shfl_xor(e2, off, 64);
            e3 += __shfl_xor(e3, off, 64);
        }
        e0 += cb;                            // t+0 < n by loop condition
        e1 = (t + 1 < n) ? e1 + cb : -INFINITY;
        e2 = (t + 2 < n) ? e2 + cb : -INFINITY;
        e3 = (t + 3 < n) ? e3 + cb : -INFINITY;

        float mn = fmaxf(fmaxf(fmaxf(e0, e1), fmaxf(e2, e3)), m);
        float alpha = __expf(m - mn);        // first iter: exp(-inf)=0
        float p0 = __expf(e0 - mn);
        float p1 = __expf(e1 - mn);          // masked rows -> 0
        float p2 = __expf(e2 - mn);
        float p3 = __expf(e3 - mn);
        l = l * alpha + (p0 + p1) + (p2 + p3);
        a0.x = a0.x*alpha + p0*x00.x + p1*x10.x + p2*x20.x + p3*x30.x;
        a0.y = a0.y*alpha + p0*x00.y + p1*x10.y + p2*x20.y + p3*x30.y;
        a0.z = a0.z*alpha + p0*x00.z + p1*x10.z + p2*x20.z + p3*x30.z;
        a0.w = a0.w*alpha + p0*x00.w + p1*x10.w + p2*x20.w + p3*x30.w;
        a1.x = a1.x*alpha + p0*x01.x + p1*x11.x + p2*x21.x + p3*x31.x;
        a1.y = a1.y*alpha + p0*x01.y + p1*x11.y + p2*x21.y + p3*x31.y;
        a1.z = a1.z*alpha + p0*x01.z + p1*x11.z + p2*x21.z + p3*x31.z;
        a1.w = a1.w*alpha + p0*x01.w + p1*x11.w + p2*x21.w + p3*x31.w;
        m = mn;
    }

    // ---- block-level merge of the 4 wave partials via LDS ----
    __shared__ float sm4[4], sl4[4];
    __shared__ float sctx[4 * H];            // 8 KB
    float4* sc = (float4*)(sctx + wave * H);
    sc[lane]      = a0;
    sc[lane + 64] = a1;
    if (lane == 0) { sm4[wave] = m; sl4[wave] = l; }
    __syncthreads();

    float M = fmaxf(fmaxf(sm4[0], sm4[1]), fmaxf(sm4[2], sm4[3]));  // finite
    float L = 0.0f, acc0 = 0.0f, acc1 = 0.0f;
#pragma unroll
    for (int j = 0; j < 4; ++j) {
        float mj = sm4[j];
        float wj = (mj == -INFINITY) ? 0.0f : __expf(mj - M);
        L += sl4[j] * wj;
        acc0 += wj * sctx[j * H + 2 * tid];
        acc1 += wj * sctx[j * H + 2 * tid + 1];
    }
    int pidx = b * NCH + blockIdx.x;
    if (tid == 0) { pm[pidx] = M; pl[pidx] = L; }
    float2* dst = (float2*)(pctx + (size_t)pidx * H);
    dst[tid] = make_float2(acc0, acc1);
}

// ---------------------------------------------------------------- kernel 3
// grid (B), block 256. nch <= 64 chunk partials per batch.
__global__ void k_combine(const float* __restrict__ pm,
                          const float* __restrict__ pl,
                          const float* __restrict__ pctx,
                          const int* __restrict__ tgt,
                          float* __restrict__ out) {
    int b = blockIdx.x;
    int tid = threadIdx.x;
    int len = tgt[b] + 1;
    int nch = (len + TT - 1) / TT;           // 1..64

    __shared__ float spm[NCH], spl[NCH];
    if (tid < nch) {
        spm[tid] = pm[b * NCH + tid];
        spl[tid] = pl[b * NCH + tid];
    }
    __syncthreads();

    float M = -INFINITY;
    for (int j = 0; j < nch; ++j) M = fmaxf(M, spm[j]);
    float L = 0.0f;
    for (int j = 0; j < nch; ++j) L += spl[j] * __expf(spm[j] - M);
    float invL = 1.0f / L;

    float acc0 = 0.0f, acc1 = 0.0f;
#pragma unroll 4
    for (int j = 0; j < nch; ++j) {
        float wj = __expf(spm[j] - M) * invL;
        float2 x = ((const float2*)(pctx + (size_t)(b * NCH + j) * H))[tid];
        acc0 += wj * x.x;
        acc1 += wj * x.y;
    }
    out[(size_t)b * H + 2 * tid]     = acc0;
    out[(size_t)b * H + 2 * tid + 1] = acc1;
}

// ---------------------------------------------------------------- launch
extern "C" void kernel_launch(void* const* d_in, const int* in_sizes, int n_in,
                              void* d_out, int out_size, void* d_ws, size_t ws_size,
                              hipStream_t stream) {
    const float* query = (const float*)d_in[0];   // [B,Q]
    const float* enc   = (const float*)d_in[1];   // [B,T,H]
    const float* W     = (const float*)d_in[2];   // [Q,H]
    const float* bias  = (const float*)d_in[3];   // [Q]
    const int*   tgt   = (const int*)d_in[4];     // [B]
    float* out = (float*)d_out;                   // [B,H]

    char* ws = (char*)d_ws;
    float* v    = (float*)ws;  ws += (size_t)B * H * sizeof(float);
    float* c    = (float*)ws;  ws += 256;
    float* pm   = (float*)ws;  ws += (size_t)B * NCH * sizeof(float);
    float* pl   = (float*)ws;  ws += (size_t)B * NCH * sizeof(float);
    float* pctx = (float*)ws;  // B * NCH * H floats = 8 MB

    k_proj<<<dim3(2, B), dim3(256), 0, stream>>>(query, W, bias, v, c);
    k_attn<<<dim3(NCH, B), dim3(256), 0, stream>>>(enc, v, c, tgt, pm, pl, pctx);
    k_combine<<<dim3(B), dim3(256), 0, stream>>>(pm, pl, pctx, tgt, out);
}